// Round 2
// baseline (398.786 us; speedup 1.0000x reference)
//
#include <hip/hip_runtime.h>

// VQ-VAE vector quantizer forward, MI355X fp32.
// x: [B=32, C=64, H=64, W=64] fp32; emb: [K=512, D=64] fp32.
// out flat order (b, h*w, c): out[g*64 + c] = emb[argmin_k dist(g,k)][c].
//
// R2 design: "fat wave" — M=4 positions/lane (xv[4][64] in VGPRs, ~290 regs,
// 1 wave/SIMD), emb row fed via SCALAR loads only (v_fmac v,s,v: the uniform
// operand costs zero issue slots; LDS/VMEM broadcast would cost a ~12-cyc
// return-bus slot per 4 floats and be pipe-bound). k-split-2 across wave
// pairs; 256 blocks = exactly 1 block/CU.

#define HWD 4096   // H*W
#define CD  64     // C == D
#define KD  512    // num_embeddings

__global__ void vq_esq_kernel(const float* __restrict__ emb, float* __restrict__ esq) {
    int k = blockIdx.x * blockDim.x + threadIdx.x;
    if (k < KD) {
        const float* er = emb + k * CD;
        float s = 0.f;
        #pragma unroll
        for (int c = 0; c < CD; ++c) s = fmaf(er[c], er[c], s);
        esq[k] = s;
    }
}

__launch_bounds__(256, 1)
__global__ void vq_main_kernel(const float* __restrict__ x,
                               const float* __restrict__ emb,
                               const float* __restrict__ esq,
                               float* __restrict__ out) {
    const int lane = threadIdx.x & 63;
    const int wv   = __builtin_amdgcn_readfirstlane(threadIdx.x >> 6);
    const int pg   = wv & 1;        // position group (0/1): 256 positions each
    const int kh   = wv >> 1;       // k half (0/1): 256 codes each

    const int g0 = blockIdx.x << 9;           // 512 positions per block
    const int b  = g0 >> 12;                  // 512 | 4096: never straddles b
    const int n0 = (g0 & 4095) + (pg << 8);

    // xv[m][c] = x[b][c][n0 + m*64 + lane]; coalesced per wave (lane-major)
    const float* xb = x + (size_t)b * (CD * HWD) + n0 + lane;
    float xv[4][CD];
    #pragma unroll
    for (int m = 0; m < 4; ++m)
        #pragma unroll
        for (int c = 0; c < CD; ++c)
            xv[m][c] = xb[(size_t)c * HWD + (m << 6)];

    const int kb = kh * (KD / 2);
    float bd0 = 3.4e38f, bd1 = 3.4e38f, bd2 = 3.4e38f, bd3 = 3.4e38f;
    int   bk0 = kb, bk1 = kb, bk2 = kb, bk3 = kb;

    for (int k = kb; k < kb + KD / 2; ++k) {
        const float* er = emb + k * CD;       // wave-uniform -> s_load chunks
        float a0 = 0.f, a1 = 0.f, a2 = 0.f, a3 = 0.f;
        #pragma unroll
        for (int c = 0; c < CD; ++c) {
            const float e = er[c];
            a0 = fmaf(xv[0][c], e, a0);
            a1 = fmaf(xv[1][c], e, a1);
            a2 = fmaf(xv[2][c], e, a2);
            a3 = fmaf(xv[3][c], e, a3);
        }
        const float eq = esq[k];              // uniform scalar load
        const float d0 = fmaf(-2.f, a0, eq);
        const float d1 = fmaf(-2.f, a1, eq);
        const float d2 = fmaf(-2.f, a2, eq);
        const float d3 = fmaf(-2.f, a3, eq);
        if (d0 < bd0) { bd0 = d0; bk0 = k; }  // strict <: lowest k on ties
        if (d1 < bd1) { bd1 = d1; bk1 = k; }
        if (d2 < bd2) { bd2 = d2; bk2 = k; }
        if (d3 < bd3) { bd3 = d3; bk3 = k; }
    }

    // Merge the two k-halves (kh=0 wins ties: only replace on strict <)
    __shared__ float sd[2][512];
    __shared__ int   sk[2][512];
    __shared__ int   sbk[512];
    const int pb = (pg << 8) + lane;
    sd[kh][pb +   0] = bd0;  sk[kh][pb +   0] = bk0;
    sd[kh][pb +  64] = bd1;  sk[kh][pb +  64] = bk1;
    sd[kh][pb + 128] = bd2;  sk[kh][pb + 128] = bk2;
    sd[kh][pb + 192] = bd3;  sk[kh][pb + 192] = bk3;
    __syncthreads();
    #pragma unroll
    for (int i = 0; i < 2; ++i) {
        int p = (i << 8) + threadIdx.x;
        float d0 = sd[0][p];
        int   kk = sk[0][p];
        if (sd[1][p] < d0) kk = sk[1][p];
        sbk[p] = kk;
    }
    __syncthreads();

    // Cooperative coalesced write, batched 4-wide (1 resident wave/SIMD:
    // batch the row loads so load->store latency isn't serialized per row)
    const size_t ob = (size_t)g0 * CD;
    for (int it = 0; it < 128; it += 4) {
        float v[4]; int ps[4];
        #pragma unroll
        for (int j = 0; j < 4; ++j) {
            int p = ((it + j) << 2) + wv;     // wave-uniform row
            ps[j] = p;
            v[j]  = emb[sbk[p] * CD + lane];  // 256-B coalesced, L2-hot
        }
        #pragma unroll
        for (int j = 0; j < 4; ++j)
            out[ob + (size_t)ps[j] * CD + lane] = v[j];
    }
}

extern "C" void kernel_launch(void* const* d_in, const int* in_sizes, int n_in,
                              void* d_out, int out_size, void* d_ws, size_t ws_size,
                              hipStream_t stream) {
    const float* x   = (const float*)d_in[0];   // 32*64*64*64
    const float* emb = (const float*)d_in[1];   // 512*64
    float* out = (float*)d_out;                 // 8388608 floats
    float* esq = (float*)d_ws;                  // 512 floats scratch

    vq_esq_kernel<<<2, 256, 0, stream>>>(emb, esq);
    vq_main_kernel<<<256, 256, 0, stream>>>(x, emb, esq, out);
}

// Round 3
// 193.532 us; speedup vs baseline: 2.0606x; 2.0606x over previous
//
#include <hip/hip_runtime.h>
#include <float.h>

// VQ-VAE vector quantizer forward, MI355X fp32.
// x: [B=32, C=64, H=64, W=64] fp32; emb: [K=512, D=64] fp32.
// out flat (b, h*w, c): out[g*64 + c] = emb[argmin_k ||x_g - emb_k||^2][c].
//
// R3: hand-rolled fp32 GEMM (X [131072x64] . embT [64x512]) with fused
// running argmin. Per wave: 16 pos x 64 k tile, per-lane 4x4 register tile
// (lane = kl + 16*pl; kl in [0,16) covers k, pl in [0,4) covers pos).
// Per c-step: 2x ds_read_b128 + 16 v_fmac — per-lane-distinct LDS reads
// (full LDS BW; no SMEM-supply or scalar-K$ dependence, no big per-lane
// arrays so no spill: C=16 + best=8 regs).

#define HWD 4096   // H*W
#define CD  64     // C == D
#define KD  512
#define PT  64     // positions per block (4 waves x 16)
#define KT  64     // k per n-tile
#define NT  (KD / KT)   // 8

__global__ void vq_esq_kernel(const float* __restrict__ emb, float* __restrict__ esq) {
    int k = blockIdx.x * blockDim.x + threadIdx.x;
    if (k < KD) {
        const float* er = emb + k * CD;
        float s = 0.f;
        #pragma unroll
        for (int c = 0; c < CD; ++c) s = fmaf(er[c], er[c], s);
        esq[k] = s;
    }
}

__launch_bounds__(256)
__global__ void vq_main_kernel(const float* __restrict__ x,
                               const float* __restrict__ emb,
                               const float* __restrict__ esq,
                               float* __restrict__ out) {
    const int tid  = threadIdx.x;
    const int lane = tid & 63;
    const int wv   = __builtin_amdgcn_readfirstlane(tid >> 6);
    const int kl   = lane & 15;   // k-lane   [0,16)
    const int pl   = lane >> 4;   // pos-lane [0,4)

    const int g0 = blockIdx.x * PT;       // first flat position
    const int b  = g0 >> 12;              // 64 | 4096: no b straddle
    const int n0 = g0 & 4095;

    __shared__ __align__(16) float xs[CD][PT];    // 16 KB, [c][pos]
    __shared__ __align__(16) float es[CD][KT];    // 16 KB, [c][k]
    __shared__ __align__(16) float esq_s[KT];
    __shared__ int bk_s[PT];

    // ---- stage x tile: [c][pos], 4096 floats, 4 float4 per thread ----
    const float* xg = x + (size_t)b * (CD * HWD) + n0;
    #pragma unroll
    for (int i = 0; i < 4; ++i) {
        int fq = i * 256 + tid;           // float4 index [0,1024)
        int c  = fq >> 4;
        int q  = fq & 15;
        float4 v = *(const float4*)(xg + (size_t)c * HWD + q * 4);
        *(float4*)&xs[c][q * 4] = v;
    }

    float bestd[4], bestk[4];
    #pragma unroll
    for (int p = 0; p < 4; ++p) { bestd[p] = FLT_MAX; bestk[p] = 0; }

    const int kk = tid & 63;              // for emb staging
    const int cq = tid >> 6;              // c-quad group [0,4)
    const float* ap = &xs[0][wv * 16 + pl * 4];
    const float* bp = &es[0][kl * 4];

    for (int nt = 0; nt < NT; ++nt) {
        __syncthreads();                  // protect es/esq_s from prev readers
        // stage emb tile transposed: es[c][k] <- emb[nt*64 + k][c]
        const float* eg = emb + (size_t)(nt * KT + kk) * CD;
        #pragma unroll
        for (int j = 0; j < 4; ++j) {
            int q = cq * 4 + j;           // c-quad [0,16)
            float4 ev = *(const float4*)(eg + q * 4);
            es[q * 4 + 0][kk] = ev.x;
            es[q * 4 + 1][kk] = ev.y;
            es[q * 4 + 2][kk] = ev.z;
            es[q * 4 + 3][kk] = ev.w;
        }
        if (tid < KT) esq_s[tid] = esq[nt * KT + tid];
        __syncthreads();

        float4 eq = *(const float4*)&esq_s[kl * 4];

        float C[4][4];
        #pragma unroll
        for (int p = 0; p < 4; ++p)
            #pragma unroll
            for (int j = 0; j < 4; ++j) C[p][j] = 0.f;

        #pragma unroll
        for (int c = 0; c < CD; ++c) {
            float4 a  = *(const float4*)(ap + c * PT);   // 4 positions
            float4 bv = *(const float4*)(bp + c * KT);   // 4 codes
            C[0][0] = fmaf(a.x, bv.x, C[0][0]);
            C[0][1] = fmaf(a.x, bv.y, C[0][1]);
            C[0][2] = fmaf(a.x, bv.z, C[0][2]);
            C[0][3] = fmaf(a.x, bv.w, C[0][3]);
            C[1][0] = fmaf(a.y, bv.x, C[1][0]);
            C[1][1] = fmaf(a.y, bv.y, C[1][1]);
            C[1][2] = fmaf(a.y, bv.z, C[1][2]);
            C[1][3] = fmaf(a.y, bv.w, C[1][3]);
            C[2][0] = fmaf(a.z, bv.x, C[2][0]);
            C[2][1] = fmaf(a.z, bv.y, C[2][1]);
            C[2][2] = fmaf(a.z, bv.z, C[2][2]);
            C[2][3] = fmaf(a.z, bv.w, C[2][3]);
            C[3][0] = fmaf(a.w, bv.x, C[3][0]);
            C[3][1] = fmaf(a.w, bv.y, C[3][1]);
            C[3][2] = fmaf(a.w, bv.z, C[3][2]);
            C[3][3] = fmaf(a.w, bv.w, C[3][3]);
        }

        // merge this n-tile into running best (j ascending, strict < :
        // lowest k wins ties, matching jnp.argmin first-index semantics)
        const int kb0 = nt * KT + kl * 4;
        #pragma unroll
        for (int p = 0; p < 4; ++p) {
            float eqj[4] = {eq.x, eq.y, eq.z, eq.w};
            #pragma unroll
            for (int j = 0; j < 4; ++j) {
                float d = fmaf(-2.f, C[p][j], eqj[j]);
                if (d < bestd[p]) { bestd[p] = d; bestk[p] = (float)0, bestk[p] = kb0 + j; }
            }
        }
    }

    // ---- cross-lane argmin over the 16 k-lanes (lane bits 0..3) ----
    int bki[4];
    #pragma unroll
    for (int p = 0; p < 4; ++p) bki[p] = (int)bestk[p];
    #pragma unroll
    for (int m = 1; m <= 8; m <<= 1) {
        #pragma unroll
        for (int p = 0; p < 4; ++p) {
            float od = __shfl_xor(bestd[p], m, 64);
            int   ok = __shfl_xor(bki[p],   m, 64);
            // composite predicate: lower distance, or equal distance & lower k
            bool take = (od < bestd[p]) || (od == bestd[p] && ok < bki[p]);
            if (take) { bestd[p] = od; bki[p] = ok; }
        }
    }
    if (kl == 0) {
        #pragma unroll
        for (int p = 0; p < 4; ++p)
            bk_s[wv * 16 + pl * 4 + p] = bki[p];
    }
    __syncthreads();

    // ---- gather epilogue: out[g][c] = emb[bk][c], coalesced, batched ----
    const size_t ob = (size_t)g0 * CD;
    for (int it = 0; it < 16; it += 4) {
        float v[4]; int pp[4];
        #pragma unroll
        for (int j = 0; j < 4; ++j) {
            int p = (it + j) * 4 + wv;            // wave-uniform position
            pp[j] = p;
            v[j]  = emb[bk_s[p] * CD + lane];     // L2-hot, 256-B coalesced
        }
        #pragma unroll
        for (int j = 0; j < 4; ++j)
            out[ob + (size_t)pp[j] * CD + lane] = v[j];
    }
}

extern "C" void kernel_launch(void* const* d_in, const int* in_sizes, int n_in,
                              void* d_out, int out_size, void* d_ws, size_t ws_size,
                              hipStream_t stream) {
    const float* x   = (const float*)d_in[0];   // 32*64*64*64
    const float* emb = (const float*)d_in[1];   // 512*64
    float* out = (float*)d_out;                 // 8388608 floats
    float* esq = (float*)d_ws;                  // 512 floats scratch

    vq_esq_kernel<<<2, 256, 0, stream>>>(emb, esq);
    vq_main_kernel<<<2048, 256, 0, stream>>>(x, emb, esq, out);
}